// Round 8
// baseline (2408.062 us; speedup 1.0000x reference)
//
#include <hip/hip_runtime.h>
#include <math.h>
#include <stdint.h>

namespace {
constexpr int N_    = 2048;
constexpr int H_    = 800;
constexpr int IN_   = 28;
constexpr int TENC  = 28;
constexpr int TTOT  = 78;             // 28 encode + 50 decode
constexpr int ONUM  = 10;
constexpr int HBLK  = 200;            // 25 it-tiles x 8 ngroups
constexpr int NBLK  = 208;            // + 8 output blocks
constexpr int PSTR  = 128;            // packed spike row stride (bytes); 104 used
constexpr int PDW   = 26;             // dwords used per packed row
constexpr int NSEG  = 13 * 4 * 2;     // (c, digit k, neuron-half) B segments
constexpr int SMEM_B = NSEG * 1024;          // 106496: fragment-ordered digit planes
constexpr int SMEM_W = IN_ * 32 * 4;         // 3584: Wi tile
constexpr int AROW  = 27;                    // LDS A-strip row stride (dwords)
constexpr int SMEM_A = 8 * 32 * AROW * 4;    // 27648: per-wave A strips
constexpr int SMEM_TOT = SMEM_B + SMEM_W + SMEM_A;  // 137728 <= 160K -> 1 blk/CU
}

typedef __attribute__((ext_vector_type(4))) int v4i;

// balanced base-256 digits of round(w * 2^32); exact for |w| < ~0.49
__device__ __forceinline__ void digitize(float w, int8_t d[4]) {
    double dd = (double)w * 4294967296.0;
    long long r = (long long)rint(dd);
    int8_t d0 = (int8_t)(r & 255); r = (r - (long long)d0) >> 8;
    int8_t d1 = (int8_t)(r & 255); r = (r - (long long)d1) >> 8;
    int8_t d2 = (int8_t)(r & 255); r = (r - (long long)d2) >> 8;
    long long r3 = r; r3 = r3 > 127 ? 127 : (r3 < -128 ? -128 : r3);
    d[0] = d0; d[1] = d1; d[2] = d2; d[3] = (int8_t)r3;
}

// expand 16 spike bits -> 16 bytes (0/1) as v4i
__device__ __forceinline__ v4i unpack16(uint32_t u) {
    v4i f;
    f[0] = (int)((((u      ) & 0xFu) * 0x00204081u) & 0x01010101u);
    f[1] = (int)((((u >>  4) & 0xFu) * 0x00204081u) & 0x01010101u);
    f[2] = (int)((((u >>  8) & 0xFu) * 0x00204081u) & 0x01010101u);
    f[3] = (int)((((u >> 12) & 0xFu) * 0x00204081u) & 0x01010101u);
    return f;
}

// ------------------- grid barrier: relaxed, no cache maintenance ------------
__device__ unsigned g_bar_cnt = 0;
__device__ unsigned g_bar_gen = 0;

__device__ __forceinline__ void grid_barrier() {
    __syncthreads();   // per-wave vmcnt(0) drain: sc1 spike stores are at LLC
    if (threadIdx.x == 0) {
        unsigned gen = __hip_atomic_load(&g_bar_gen, __ATOMIC_RELAXED, __HIP_MEMORY_SCOPE_AGENT);
        unsigned arr = __hip_atomic_fetch_add(&g_bar_cnt, 1u, __ATOMIC_RELAXED, __HIP_MEMORY_SCOPE_AGENT);
        if (arr == (unsigned)(NBLK - 1)) {
            __hip_atomic_store(&g_bar_cnt, 0u, __ATOMIC_RELAXED, __HIP_MEMORY_SCOPE_AGENT);
            asm volatile("s_waitcnt vmcnt(0)" ::: "memory");  // cnt reset visible first
            __hip_atomic_fetch_add(&g_bar_gen, 1u, __ATOMIC_RELAXED, __HIP_MEMORY_SCOPE_AGENT);
        } else {
            while (__hip_atomic_load(&g_bar_gen, __ATOMIC_RELAXED, __HIP_MEMORY_SCOPE_AGENT) == gen)
                __builtin_amdgcn_s_sleep(8);
        }
    }
    __syncthreads();
}

// ---------------------------------------------------------------------------
// prepass: transpose x into xt2[t][n][c], zero packed spike buffers, init state
// ---------------------------------------------------------------------------
__global__ void prep_kernel(const float* __restrict__ x, float* __restrict__ xt2,
                            uint32_t* __restrict__ sp0, uint32_t* __restrict__ sp1,
                            float* __restrict__ hmG, float* __restrict__ hbG)
{
    size_t idx = (size_t)blockIdx.x * blockDim.x + threadIdx.x;
    size_t stride = (size_t)gridDim.x * blockDim.x;
    const size_t TOT = (size_t)TENC * N_ * IN_;
    for (size_t e = idx; e < TOT; e += stride) {
        int t = (int)(e / (N_ * IN_));
        int rem = (int)(e % (N_ * IN_));
        int n = rem / IN_, c = rem % IN_;
        xt2[e] = x[(size_t)n * 784 + c * TENC + t];
    }
    const size_t PW = (size_t)N_ * PSTR / 4;
    for (size_t e = idx; e < PW; e += stride) { sp0[e] = 0u; sp1[e] = 0u; }
    const size_t ST = (size_t)HBLK * 8 * 1024;
    for (size_t e = idx; e < ST; e += stride) { hmG[e] = 0.f; hbG[e] = 0.01f; }
}

// ---------------------------------------------------------------------------
// Persistent LSNN: 200 hidden blocks (32 neurons x 256 samples) + 8 o-blocks.
// B digit planes in LDS, spikes bit-packed + sc1-coherent in global,
// hm/hb in block-private global (L2-resident), prev-spikes as a bitmask reg.
// ---------------------------------------------------------------------------
__global__ __launch_bounds__(512, 2)
void lsnn_persist(const float* __restrict__ xt2,
                  const float* __restrict__ Wi,
                  const float* __restrict__ b_i2h,
                  const float* __restrict__ Wh,
                  const float* __restrict__ b_h2h,
                  const float* __restrict__ Wo,
                  const float* __restrict__ b_h2o,
                  const float* __restrict__ tau_h,
                  const float* __restrict__ tau_o,
                  uint32_t* sp0, uint32_t* sp1,
                  float* __restrict__ hmG, float* __restrict__ hbG,
                  float* __restrict__ out)
{
    extern __shared__ __align__(16) int8_t smem[];
    int8_t*   Bl  = smem;                                   // [NSEG][64][16]
    float*    wl  = (float*)(smem + SMEM_B);                // [28][32]
    uint32_t* Alds = (uint32_t*)(smem + SMEM_B + SMEM_W);   // [8 waves][32][AROW]

    const int bid  = blockIdx.x;
    const bool is_o = (bid >= HBLK);
    const int it   = is_o ? 0 : (bid % 25);
    const int ng   = is_o ? (bid - HBLK) : (bid / 25);
    const int i0   = it * 32;
    const int wv   = threadIdx.x >> 6;
    const int lane = threadIdx.x & 63;
    const int quad = lane >> 4;
    const int col  = lane & 15;
    const int n0   = ng * 256 + wv * 32;
    uint32_t* ldsA = Alds + wv * 32 * AROW;
    const int dsel = (quad >> 1);            // dword select within 8-byte group
    const int dsh  = (quad & 1) * 16;        // shift within dword

    // ---- build B digit fragments in LDS (once) ----
    for (int e = threadIdx.x; e < 13 * 2 * 64; e += 512) {
        int c  = e >> 7;
        int bh = (e >> 6) & 1;
        int ln = e & 63;
        int q  = ln >> 4, cl = ln & 15;
        int kbase = c * 64 + q * 16;
        uint32_t w4[4][4] = {};
        int row = bh * 16 + cl;
        #pragma unroll
        for (int j = 0; j < 16; ++j) {
            int kidx = kbase + j;
            float w = 0.f;
            if (kidx < H_) {
                if (!is_o) w = Wh[(size_t)(i0 + row) * H_ + kidx];
                else if (bh == 0 && cl < ONUM) w = Wo[(size_t)cl * H_ + kidx];
            }
            int8_t d[4]; digitize(w, d);
            #pragma unroll
            for (int k = 0; k < 4; ++k)
                w4[k][j >> 2] |= ((uint32_t)(uint8_t)d[k]) << ((j & 3) * 8);
        }
        #pragma unroll
        for (int k = 0; k < 4; ++k) {
            v4i v; v[0] = (int)w4[k][0]; v[1] = (int)w4[k][1];
            v[2] = (int)w4[k][2]; v[3] = (int)w4[k][3];
            *(v4i*)(Bl + (((c * 8) + k * 2 + bh) << 10) + (ln << 4)) = v;
        }
    }
    if (!is_o) {
        for (int e = threadIdx.x; e < IN_ * 32; e += 512) {
            int c = e >> 5, il = e & 31;
            wl[c * 32 + il] = Wi[(size_t)(i0 + il) * IN_ + c];
        }
    }

    // ---- constants & register state ----
    const float alpha = (float)exp((double)(-1.0f / 20.0f));
    const float onem  = 1.0f - alpha;
    const double INV32 = 1.0 / 4294967296.0;

    float roB[2] = {}, biB[2] = {}, bhB[2] = {};
    float om[2][4] = {}, ospv[2][4] = {}, obb[2][4], cnt[2][4] = {};
    float roO = 0.f, boO = 0.f;
    uint32_t pmask = 0;   // prev spikes for this lane's 16 outputs

    float* hmW = hmG + (((size_t)bid * 8 + wv) << 10);
    float* hbW = hbG + (((size_t)bid * 8 + wv) << 10);

    if (!is_o) {
        #pragma unroll
        for (int b = 0; b < 2; ++b) {
            int i = i0 + b * 16 + col;
            float arg = -1.0f / tau_h[i];
            roB[b] = (float)exp((double)arg);
            biB[b] = b_i2h[i]; bhB[b] = b_h2h[i];
        }
    } else {
        if (col < ONUM) {
            float arg = -1.0f / tau_o[col];
            roO = (float)exp((double)arg);
            boO = b_h2o[col];
        }
        #pragma unroll
        for (int a = 0; a < 2; ++a)
            #pragma unroll
            for (int r = 0; r < 4; ++r) obb[a][r] = 0.01f;
    }

    __syncthreads();
    grid_barrier();

    // ---- time loop ----
    for (int t = 0; t <= TTOT; ++t) {
        const uint32_t* rdP = (t & 1) ? sp1 : sp0;
        uint32_t*       wrP = (t & 1) ? sp0 : sp1;

        const bool active = is_o ? (t >= 1) : (t < TTOT);

        if (active) {
            // ---- stage this wave's 32 packed A rows into LDS (coalesced sc1) ----
            #pragma unroll
            for (int k = 0; k < 13; ++k) {
                int e = k * 64 + lane;             // 0..831
                int row = e / PDW, d = e - row * PDW;
                uint32_t v = __hip_atomic_load(rdP + (size_t)(n0 + row) * (PSTR / 4) + d,
                                               __ATOMIC_RELAXED, __HIP_MEMORY_SCOPE_AGENT);
                ldsA[row * AROW + d] = v;
            }
        }

        if (!is_o && active) {
            // input projection (encode steps): fp64 exact, fp32-rounded once
            float inpf[2][2][4] = {};
            if (t < TENC) {
                #pragma unroll
                for (int a = 0; a < 2; ++a) {
                    #pragma unroll
                    for (int r = 0; r < 4; ++r) {
                        int n = n0 + a * 16 + quad * 4 + r;
                        const float* xp = xt2 + ((size_t)t * N_ + n) * IN_;
                        double s0 = 0.0, s1 = 0.0;
                        #pragma unroll
                        for (int c = 0; c < IN_; ++c) {
                            double xv = (double)xp[c];
                            s0 += xv * (double)wl[c * 32 + col];
                            s1 += xv * (double)wl[c * 32 + 16 + col];
                        }
                        inpf[a][0][r] = (float)s0;
                        inpf[a][1][r] = (float)s1;
                    }
                }
            }

            v4i acc4[2][2][4] = {};
            #pragma unroll
            for (int c = 0; c < 13; ++c) {
                uint32_t d0 = ldsA[col * AROW + c * 2 + dsel];
                uint32_t d1 = ldsA[(16 + col) * AROW + c * 2 + dsel];
                v4i a0 = unpack16((d0 >> dsh) & 0xFFFFu);
                v4i a1 = unpack16((d1 >> dsh) & 0xFFFFu);
                #pragma unroll
                for (int k = 0; k < 4; ++k) {
                    v4i b0 = *(const v4i*)(Bl + (((c * 8) + k * 2 + 0) << 10) + (lane << 4));
                    v4i b1 = *(const v4i*)(Bl + (((c * 8) + k * 2 + 1) << 10) + (lane << 4));
                    acc4[0][0][k] = __builtin_amdgcn_mfma_i32_16x16x64_i8(a0, b0, acc4[0][0][k], 0, 0, 0);
                    acc4[0][1][k] = __builtin_amdgcn_mfma_i32_16x16x64_i8(a0, b1, acc4[0][1][k], 0, 0, 0);
                    acc4[1][0][k] = __builtin_amdgcn_mfma_i32_16x16x64_i8(a1, b0, acc4[1][0][k], 0, 0, 0);
                    acc4[1][1][k] = __builtin_amdgcn_mfma_i32_16x16x64_i8(a1, b1, acc4[1][1][k], 0, 0, 0);
                }
            }

            // hidden epilogue: fp32, reference order, no FMA; state in L2 global
            uint32_t nmask = 0;
            {
                #pragma clang fp contract(off)
                #pragma unroll
                for (int a = 0; a < 2; ++a) {
                    #pragma unroll
                    for (int b = 0; b < 2; ++b) {
                        #pragma unroll
                        for (int r = 0; r < 4; ++r) {
                            int sidx = ((a * 2 + b) * 4 + r);
                            int soff = (sidx << 6) + lane;
                            int64_t tot = ((int64_t)acc4[a][b][3][r] << 24)
                                        + ((int64_t)acc4[a][b][2][r] << 16)
                                        + ((int64_t)acc4[a][b][1][r] << 8)
                                        +  (int64_t)acc4[a][b][0][r];
                            float rec = (float)((double)tot * INV32);
                            float h_in = ((inpf[a][b][r] + biB[b]) + rec) + bhB[b];
                            float sp = (pmask >> sidx) & 1u ? 1.0f : 0.0f;
                            float ro = roB[b];
                            float bnew = (ro * hbW[soff]) + ((1.0f - ro) * sp);
                            float B = 0.01f + (1.8f * bnew);
                            float mem = ((hmW[soff] * alpha) + (onem * h_in)) - (B * sp);
                            float s = (mem - B) > 0.f ? 1.f : 0.f;
                            hbW[soff] = bnew; hmW[soff] = mem;
                            if (s > 0.5f) nmask |= (1u << sidx);
                        }
                    }
                }
            }
            pmask = nmask;

            // pack spikes: ballots -> one 32-bit word per row (this block's i-tile)
            #pragma unroll
            for (int a = 0; a < 2; ++a) {
                #pragma unroll
                for (int r = 0; r < 4; ++r) {
                    unsigned long long bal0 = __ballot((nmask >> (a * 8 + r)) & 1u);
                    unsigned long long bal1 = __ballot((nmask >> (a * 8 + 4 + r)) & 1u);
                    if (col == a * 4 + r) {
                        uint32_t w = (uint32_t)((bal0 >> (quad * 16)) & 0xFFFFull)
                                   | ((uint32_t)((bal1 >> (quad * 16)) & 0xFFFFull) << 16);
                        int n = n0 + a * 16 + quad * 4 + r;
                        __hip_atomic_store(wrP + (size_t)n * (PSTR / 4) + it, w,
                                           __ATOMIC_RELAXED, __HIP_MEMORY_SCOPE_AGENT);
                    }
                }
            }
        }

        if (is_o && active) {
            v4i oacc[2][4] = {};
            #pragma unroll
            for (int c = 0; c < 13; ++c) {
                uint32_t d0 = ldsA[col * AROW + c * 2 + dsel];
                uint32_t d1 = ldsA[(16 + col) * AROW + c * 2 + dsel];
                v4i a0 = unpack16((d0 >> dsh) & 0xFFFFu);
                v4i a1 = unpack16((d1 >> dsh) & 0xFFFFu);
                #pragma unroll
                for (int k = 0; k < 4; ++k) {
                    v4i bo = *(const v4i*)(Bl + (((c * 8) + k * 2 + 0) << 10) + (lane << 4));
                    oacc[0][k] = __builtin_amdgcn_mfma_i32_16x16x64_i8(a0, bo, oacc[0][k], 0, 0, 0);
                    oacc[1][k] = __builtin_amdgcn_mfma_i32_16x16x64_i8(a1, bo, oacc[1][k], 0, 0, 0);
                }
            }
            if (col < ONUM) {
                #pragma clang fp contract(off)
                const bool msk = (t - 1) >= TENC;
                #pragma unroll
                for (int a = 0; a < 2; ++a) {
                    #pragma unroll
                    for (int r = 0; r < 4; ++r) {
                        int64_t tot = ((int64_t)oacc[a][3][r] << 24)
                                    + ((int64_t)oacc[a][2][r] << 16)
                                    + ((int64_t)oacc[a][1][r] << 8)
                                    +  (int64_t)oacc[a][0][r];
                        float o_in = ((float)((double)tot * INV32)) + boO;
                        float osp_ = ospv[a][r];
                        float bnew = (roO * obb[a][r]) + ((1.0f - roO) * osp_);
                        float B = 0.01f + (1.8f * bnew);
                        float mem = ((om[a][r] * alpha) + (onem * o_in)) - (B * osp_);
                        float s = (mem - B) > 0.f ? 1.f : 0.f;
                        obb[a][r] = bnew; om[a][r] = mem; ospv[a][r] = s;
                        if (msk) cnt[a][r] += s;
                    }
                }
            }
        }

        if (t < TTOT) grid_barrier();
    }

    // ---- write spike counts ----
    if (is_o && col < ONUM) {
        #pragma unroll
        for (int a = 0; a < 2; ++a)
            #pragma unroll
            for (int r = 0; r < 4; ++r) {
                int n = n0 + a * 16 + quad * 4 + r;
                out[(size_t)n * ONUM + col] = cnt[a][r];
            }
    }
}

// ---------------------------------------------------------------------------
extern "C" void kernel_launch(void* const* d_in, const int* in_sizes, int n_in,
                              void* d_out, int out_size, void* d_ws, size_t ws_size,
                              hipStream_t stream)
{
    const float* x      = (const float*)d_in[0];
    const float* Wi     = (const float*)d_in[1];
    const float* b_i2h  = (const float*)d_in[2];
    const float* Wh     = (const float*)d_in[3];
    const float* b_h2h  = (const float*)d_in[4];
    const float* Wo     = (const float*)d_in[5];
    const float* b_h2o  = (const float*)d_in[6];
    const float* tau_h  = (const float*)d_in[7];
    const float* tau_o  = (const float*)d_in[8];
    float* out = (float*)d_out;

    uintptr_t p = (uintptr_t)d_ws;
    auto alloc = [&](size_t bytes) -> void* {
        p = (p + 255) & ~(uintptr_t)255;
        void* r = (void*)p; p += bytes; return r;
    };
    uint32_t* sp0 = (uint32_t*)alloc((size_t)N_ * PSTR);
    uint32_t* sp1 = (uint32_t*)alloc((size_t)N_ * PSTR);
    float*    xt2 = (float*)alloc((size_t)TENC * N_ * IN_ * 4);
    float*    hmG = (float*)alloc((size_t)HBLK * 8 * 1024 * 4);
    float*    hbG = (float*)alloc((size_t)HBLK * 8 * 1024 * 4);

    prep_kernel<<<1024, 256, 0, stream>>>(x, xt2, sp0, sp1, hmG, hbG);

    (void)hipFuncSetAttribute((const void*)lsnn_persist,
                              hipFuncAttributeMaxDynamicSharedMemorySize, SMEM_TOT);
    lsnn_persist<<<NBLK, 512, SMEM_TOT, stream>>>(
        xt2, Wi, b_i2h, Wh, b_h2h, Wo, b_h2o, tau_h, tau_o,
        sp0, sp1, hmG, hbG, out);
}

// Round 9
// 1571.657 us; speedup vs baseline: 1.5322x; 1.5322x over previous
//
#include <hip/hip_runtime.h>
#include <math.h>
#include <stdint.h>

namespace {
constexpr int N_    = 2048;
constexpr int H_    = 800;
constexpr int IN_   = 28;
constexpr int TENC  = 28;
constexpr int TTOT  = 78;             // 28 encode + 50 decode
constexpr int ONUM  = 10;
constexpr int HBLK  = 200;            // 25 it-tiles x 8 ngroups
constexpr int NBLK  = 208;            // + 8 output blocks
constexpr int PSTR  = 128;            // packed spike row stride (bytes); 104 used
constexpr int PDW   = 26;             // dwords used per packed row
constexpr int NSEG  = 13 * 4 * 2;     // (c, digit k, neuron-half) B segments
constexpr int SMEM_B = NSEG * 1024;          // 106496: fragment-ordered digit planes
constexpr int SMEM_W = IN_ * 32 * 4;         // 3584: Wi tile
constexpr int AROW  = 27;                    // LDS A-strip row stride (dwords)
constexpr int SMEM_A = 8 * 32 * AROW * 4;    // 27648: per-wave A strips
constexpr int SMEM_TOT = SMEM_B + SMEM_W + SMEM_A;  // 137728 <= 160K -> 1 blk/CU
}

typedef __attribute__((ext_vector_type(4))) int v4i;

// balanced base-256 digits of round(w * 2^32); exact for |w| < ~0.49
__device__ __forceinline__ void digitize(float w, int8_t d[4]) {
    double dd = (double)w * 4294967296.0;
    long long r = (long long)rint(dd);
    int8_t d0 = (int8_t)(r & 255); r = (r - (long long)d0) >> 8;
    int8_t d1 = (int8_t)(r & 255); r = (r - (long long)d1) >> 8;
    int8_t d2 = (int8_t)(r & 255); r = (r - (long long)d2) >> 8;
    long long r3 = r; r3 = r3 > 127 ? 127 : (r3 < -128 ? -128 : r3);
    d[0] = d0; d[1] = d1; d[2] = d2; d[3] = (int8_t)r3;
}

// expand 16 spike bits -> 16 bytes (0/1) as v4i
__device__ __forceinline__ v4i unpack16(uint32_t u) {
    v4i f;
    f[0] = (int)((((u      ) & 0xFu) * 0x00204081u) & 0x01010101u);
    f[1] = (int)((((u >>  4) & 0xFu) * 0x00204081u) & 0x01010101u);
    f[2] = (int)((((u >>  8) & 0xFu) * 0x00204081u) & 0x01010101u);
    f[3] = (int)((((u >> 12) & 0xFu) * 0x00204081u) & 0x01010101u);
    return f;
}

// ---- contention-free grid barrier: per-block flag lines + master scan ------
__device__ __forceinline__ void flag_barrier(uint32_t* __restrict__ flags,
                                             uint32_t* __restrict__ genp,
                                             int bid, uint32_t epoch) {
    __syncthreads();   // all waves drain vmcnt before passing (spike stores at LLC)
    const int tid = threadIdx.x;
    if (tid == 0) {
        asm volatile("s_waitcnt vmcnt(0)" ::: "memory");
        __hip_atomic_store(flags + (size_t)bid * 16, epoch,
                           __ATOMIC_RELAXED, __HIP_MEMORY_SCOPE_AGENT);
    }
    if (bid == 0) {
        if (tid < 64) {   // wave 0 scans all flags
            bool done = false;
            while (!done) {
                bool ok = true;
                #pragma unroll
                for (int k = 0; k < 4; ++k) {
                    int f = tid + k * 64;
                    if (f < NBLK)
                        ok &= (__hip_atomic_load(flags + (size_t)f * 16,
                                __ATOMIC_RELAXED, __HIP_MEMORY_SCOPE_AGENT) >= epoch);
                }
                done = (__ballot(ok) == ~0ull);
                if (!done) __builtin_amdgcn_s_sleep(1);
            }
            if (tid == 0)
                __hip_atomic_store(genp, epoch, __ATOMIC_RELAXED, __HIP_MEMORY_SCOPE_AGENT);
        }
    } else if (tid == 0) {
        while (__hip_atomic_load(genp, __ATOMIC_RELAXED, __HIP_MEMORY_SCOPE_AGENT) < epoch)
            __builtin_amdgcn_s_sleep(1);
    }
    __syncthreads();
}

// ---------------------------------------------------------------------------
// prepass: transpose x into xt2[t][n][c], zero packed spike buffers + flags
// ---------------------------------------------------------------------------
__global__ void prep_kernel(const float* __restrict__ x, float* __restrict__ xt2,
                            uint32_t* __restrict__ sp0, uint32_t* __restrict__ sp1,
                            uint32_t* __restrict__ flags)
{
    size_t idx = (size_t)blockIdx.x * blockDim.x + threadIdx.x;
    size_t stride = (size_t)gridDim.x * blockDim.x;
    const size_t TOT = (size_t)TENC * N_ * IN_;
    for (size_t e = idx; e < TOT; e += stride) {
        int t = (int)(e / (N_ * IN_));
        int rem = (int)(e % (N_ * IN_));
        int n = rem / IN_, c = rem % IN_;
        xt2[e] = x[(size_t)n * 784 + c * TENC + t];
    }
    const size_t PW = (size_t)N_ * PSTR / 4;
    for (size_t e = idx; e < PW; e += stride) { sp0[e] = 0u; sp1[e] = 0u; }
    for (size_t e = idx; e < (size_t)(NBLK + 1) * 16; e += stride) flags[e] = 0u;
}

// ---------------------------------------------------------------------------
// Persistent LSNN: 200 hidden blocks (32 neurons x 256 samples) + 8 o-blocks.
// B digit planes in LDS, spikes bit-packed + sc1-coherent in global,
// ALL neuron state in registers. Flag-based grid barrier (no atomic RMW).
// ---------------------------------------------------------------------------
__global__ __launch_bounds__(512, 2)
void lsnn_persist(const float* __restrict__ xt2,
                  const float* __restrict__ Wi,
                  const float* __restrict__ b_i2h,
                  const float* __restrict__ Wh,
                  const float* __restrict__ b_h2h,
                  const float* __restrict__ Wo,
                  const float* __restrict__ b_h2o,
                  const float* __restrict__ tau_h,
                  const float* __restrict__ tau_o,
                  uint32_t* sp0, uint32_t* sp1,
                  uint32_t* flags, uint32_t* genp,
                  float* __restrict__ out)
{
    extern __shared__ __align__(16) int8_t smem[];
    int8_t*   Bl  = smem;                                   // [NSEG][64][16]
    float*    wl  = (float*)(smem + SMEM_B);                // [28][32]
    uint32_t* Alds = (uint32_t*)(smem + SMEM_B + SMEM_W);   // [8 waves][32][AROW]

    const int bid  = blockIdx.x;
    const bool is_o = (bid >= HBLK);
    const int it   = is_o ? 0 : (bid % 25);
    const int ng   = is_o ? (bid - HBLK) : (bid / 25);
    const int i0   = it * 32;
    const int wv   = threadIdx.x >> 6;
    const int lane = threadIdx.x & 63;
    const int quad = lane >> 4;
    const int col  = lane & 15;
    const int n0   = ng * 256 + wv * 32;
    uint32_t* ldsA = Alds + wv * 32 * AROW;
    const int dsel = (quad >> 1);
    const int dsh  = (quad & 1) * 16;

    // ---- build B digit fragments in LDS (once) ----
    for (int e = threadIdx.x; e < 13 * 2 * 64; e += 512) {
        int c  = e >> 7;
        int bh = (e >> 6) & 1;
        int ln = e & 63;
        int q  = ln >> 4, cl = ln & 15;
        int kbase = c * 64 + q * 16;
        uint32_t w4[4][4] = {};
        int row = bh * 16 + cl;
        #pragma unroll
        for (int j = 0; j < 16; ++j) {
            int kidx = kbase + j;
            float w = 0.f;
            if (kidx < H_) {
                if (!is_o) w = Wh[(size_t)(i0 + row) * H_ + kidx];
                else if (bh == 0 && cl < ONUM) w = Wo[(size_t)cl * H_ + kidx];
            }
            int8_t d[4]; digitize(w, d);
            #pragma unroll
            for (int k = 0; k < 4; ++k)
                w4[k][j >> 2] |= ((uint32_t)(uint8_t)d[k]) << ((j & 3) * 8);
        }
        #pragma unroll
        for (int k = 0; k < 4; ++k) {
            v4i v; v[0] = (int)w4[k][0]; v[1] = (int)w4[k][1];
            v[2] = (int)w4[k][2]; v[3] = (int)w4[k][3];
            *(v4i*)(Bl + (((c * 8) + k * 2 + bh) << 10) + (ln << 4)) = v;
        }
    }
    if (!is_o) {
        for (int e = threadIdx.x; e < IN_ * 32; e += 512) {
            int c = e >> 5, il = e & 31;
            wl[c * 32 + il] = Wi[(size_t)(i0 + il) * IN_ + c];
        }
    }

    // ---- constants & register state ----
    const float alpha = (float)exp((double)(-1.0f / 20.0f));
    const float onem  = 1.0f - alpha;
    const double INV32 = 1.0 / 4294967296.0;

    float roB[2] = {}, biB[2] = {}, bhB[2] = {};
    float hm[2][2][4] = {}, hbv[2][2][4];
    float om[2][4] = {}, ospv[2][4] = {}, obb[2][4], cnt[2][4] = {};
    float roO = 0.f, boO = 0.f;
    uint32_t pmask = 0;   // prev spikes for this lane's 16 outputs

    if (!is_o) {
        #pragma unroll
        for (int b = 0; b < 2; ++b) {
            int i = i0 + b * 16 + col;
            float arg = -1.0f / tau_h[i];
            roB[b] = (float)exp((double)arg);
            biB[b] = b_i2h[i]; bhB[b] = b_h2h[i];
        }
        #pragma unroll
        for (int a = 0; a < 2; ++a)
            #pragma unroll
            for (int b = 0; b < 2; ++b)
                #pragma unroll
                for (int r = 0; r < 4; ++r) hbv[a][b][r] = 0.01f;
    } else {
        if (col < ONUM) {
            float arg = -1.0f / tau_o[col];
            roO = (float)exp((double)arg);
            boO = b_h2o[col];
        }
        #pragma unroll
        for (int a = 0; a < 2; ++a)
            #pragma unroll
            for (int r = 0; r < 4; ++r) obb[a][r] = 0.01f;
    }

    uint32_t epoch = 1;
    flag_barrier(flags, genp, bid, epoch++);

    // ---- time loop ----
    for (int t = 0; t <= TTOT; ++t) {
        const uint32_t* rdP = (t & 1) ? sp1 : sp0;
        uint32_t*       wrP = (t & 1) ? sp0 : sp1;

        const bool active = is_o ? (t >= 1) : (t < TTOT);

        if (active) {
            // stage this wave's 32 packed A rows into LDS (coalesced sc1)
            #pragma unroll
            for (int k = 0; k < 13; ++k) {
                int e = k * 64 + lane;
                int row = e / PDW, d = e - row * PDW;
                uint32_t v = __hip_atomic_load(rdP + (size_t)(n0 + row) * (PSTR / 4) + d,
                                               __ATOMIC_RELAXED, __HIP_MEMORY_SCOPE_AGENT);
                ldsA[row * AROW + d] = v;
            }
        }

        if (!is_o && active) {
            // input projection (encode steps): fp64 exact, fp32-rounded once
            float inpf[2][2][4] = {};
            if (t < TENC) {
                #pragma unroll
                for (int a = 0; a < 2; ++a) {
                    #pragma unroll
                    for (int r = 0; r < 4; ++r) {
                        int n = n0 + a * 16 + quad * 4 + r;
                        const float* xp = xt2 + ((size_t)t * N_ + n) * IN_;
                        double s0 = 0.0, s1 = 0.0;
                        #pragma unroll
                        for (int c = 0; c < IN_; ++c) {
                            double xv = (double)xp[c];
                            s0 += xv * (double)wl[c * 32 + col];
                            s1 += xv * (double)wl[c * 32 + 16 + col];
                        }
                        inpf[a][0][r] = (float)s0;
                        inpf[a][1][r] = (float)s1;
                    }
                }
            }

            v4i acc4[2][2][4] = {};
            #pragma unroll
            for (int c = 0; c < 13; ++c) {
                uint32_t d0 = ldsA[col * AROW + c * 2 + dsel];
                uint32_t d1 = ldsA[(16 + col) * AROW + c * 2 + dsel];
                v4i a0 = unpack16((d0 >> dsh) & 0xFFFFu);
                v4i a1 = unpack16((d1 >> dsh) & 0xFFFFu);
                #pragma unroll
                for (int k = 0; k < 4; ++k) {
                    v4i b0 = *(const v4i*)(Bl + (((c * 8) + k * 2 + 0) << 10) + (lane << 4));
                    v4i b1 = *(const v4i*)(Bl + (((c * 8) + k * 2 + 1) << 10) + (lane << 4));
                    acc4[0][0][k] = __builtin_amdgcn_mfma_i32_16x16x64_i8(a0, b0, acc4[0][0][k], 0, 0, 0);
                    acc4[0][1][k] = __builtin_amdgcn_mfma_i32_16x16x64_i8(a0, b1, acc4[0][1][k], 0, 0, 0);
                    acc4[1][0][k] = __builtin_amdgcn_mfma_i32_16x16x64_i8(a1, b0, acc4[1][0][k], 0, 0, 0);
                    acc4[1][1][k] = __builtin_amdgcn_mfma_i32_16x16x64_i8(a1, b1, acc4[1][1][k], 0, 0, 0);
                }
            }

            // hidden epilogue: fp32, reference order, no FMA; state in registers
            uint32_t nmask = 0;
            {
                #pragma clang fp contract(off)
                #pragma unroll
                for (int a = 0; a < 2; ++a) {
                    #pragma unroll
                    for (int b = 0; b < 2; ++b) {
                        #pragma unroll
                        for (int r = 0; r < 4; ++r) {
                            int sidx = ((a * 2 + b) * 4 + r);
                            int64_t tot = ((int64_t)acc4[a][b][3][r] << 24)
                                        + ((int64_t)acc4[a][b][2][r] << 16)
                                        + ((int64_t)acc4[a][b][1][r] << 8)
                                        +  (int64_t)acc4[a][b][0][r];
                            float rec = (float)((double)tot * INV32);
                            float h_in = ((inpf[a][b][r] + biB[b]) + rec) + bhB[b];
                            float sp = (pmask >> sidx) & 1u ? 1.0f : 0.0f;
                            float ro = roB[b];
                            float bnew = (ro * hbv[a][b][r]) + ((1.0f - ro) * sp);
                            float B = 0.01f + (1.8f * bnew);
                            float mem = ((hm[a][b][r] * alpha) + (onem * h_in)) - (B * sp);
                            float s = (mem - B) > 0.f ? 1.f : 0.f;
                            hbv[a][b][r] = bnew; hm[a][b][r] = mem;
                            if (s > 0.5f) nmask |= (1u << sidx);
                        }
                    }
                }
            }
            pmask = nmask;

            // pack spikes: ballots -> one 32-bit word per row (this block's i-tile)
            #pragma unroll
            for (int a = 0; a < 2; ++a) {
                #pragma unroll
                for (int r = 0; r < 4; ++r) {
                    unsigned long long bal0 = __ballot((nmask >> (a * 8 + r)) & 1u);
                    unsigned long long bal1 = __ballot((nmask >> (a * 8 + 4 + r)) & 1u);
                    if (col == a * 4 + r) {
                        uint32_t w = (uint32_t)((bal0 >> (quad * 16)) & 0xFFFFull)
                                   | ((uint32_t)((bal1 >> (quad * 16)) & 0xFFFFull) << 16);
                        int n = n0 + a * 16 + quad * 4 + r;
                        __hip_atomic_store(wrP + (size_t)n * (PSTR / 4) + it, w,
                                           __ATOMIC_RELAXED, __HIP_MEMORY_SCOPE_AGENT);
                    }
                }
            }
        }

        if (is_o && active) {
            v4i oacc[2][4] = {};
            #pragma unroll
            for (int c = 0; c < 13; ++c) {
                uint32_t d0 = ldsA[col * AROW + c * 2 + dsel];
                uint32_t d1 = ldsA[(16 + col) * AROW + c * 2 + dsel];
                v4i a0 = unpack16((d0 >> dsh) & 0xFFFFu);
                v4i a1 = unpack16((d1 >> dsh) & 0xFFFFu);
                #pragma unroll
                for (int k = 0; k < 4; ++k) {
                    v4i bo = *(const v4i*)(Bl + (((c * 8) + k * 2 + 0) << 10) + (lane << 4));
                    oacc[0][k] = __builtin_amdgcn_mfma_i32_16x16x64_i8(a0, bo, oacc[0][k], 0, 0, 0);
                    oacc[1][k] = __builtin_amdgcn_mfma_i32_16x16x64_i8(a1, bo, oacc[1][k], 0, 0, 0);
                }
            }
            if (col < ONUM) {
                #pragma clang fp contract(off)
                const bool msk = (t - 1) >= TENC;
                #pragma unroll
                for (int a = 0; a < 2; ++a) {
                    #pragma unroll
                    for (int r = 0; r < 4; ++r) {
                        int64_t tot = ((int64_t)oacc[a][3][r] << 24)
                                    + ((int64_t)oacc[a][2][r] << 16)
                                    + ((int64_t)oacc[a][1][r] << 8)
                                    +  (int64_t)oacc[a][0][r];
                        float o_in = ((float)((double)tot * INV32)) + boO;
                        float osp_ = ospv[a][r];
                        float bnew = (roO * obb[a][r]) + ((1.0f - roO) * osp_);
                        float B = 0.01f + (1.8f * bnew);
                        float mem = ((om[a][r] * alpha) + (onem * o_in)) - (B * osp_);
                        float s = (mem - B) > 0.f ? 1.f : 0.f;
                        obb[a][r] = bnew; om[a][r] = mem; ospv[a][r] = s;
                        if (msk) cnt[a][r] += s;
                    }
                }
            }
        }

        if (t < TTOT) flag_barrier(flags, genp, bid, epoch++);
    }

    // ---- write spike counts ----
    if (is_o && col < ONUM) {
        #pragma unroll
        for (int a = 0; a < 2; ++a)
            #pragma unroll
            for (int r = 0; r < 4; ++r) {
                int n = n0 + a * 16 + quad * 4 + r;
                out[(size_t)n * ONUM + col] = cnt[a][r];
            }
    }
}

// ---------------------------------------------------------------------------
extern "C" void kernel_launch(void* const* d_in, const int* in_sizes, int n_in,
                              void* d_out, int out_size, void* d_ws, size_t ws_size,
                              hipStream_t stream)
{
    const float* x      = (const float*)d_in[0];
    const float* Wi     = (const float*)d_in[1];
    const float* b_i2h  = (const float*)d_in[2];
    const float* Wh     = (const float*)d_in[3];
    const float* b_h2h  = (const float*)d_in[4];
    const float* Wo     = (const float*)d_in[5];
    const float* b_h2o  = (const float*)d_in[6];
    const float* tau_h  = (const float*)d_in[7];
    const float* tau_o  = (const float*)d_in[8];
    float* out = (float*)d_out;

    uintptr_t p = (uintptr_t)d_ws;
    auto alloc = [&](size_t bytes) -> void* {
        p = (p + 255) & ~(uintptr_t)255;
        void* r = (void*)p; p += bytes; return r;
    };
    uint32_t* sp0   = (uint32_t*)alloc((size_t)N_ * PSTR);
    uint32_t* sp1   = (uint32_t*)alloc((size_t)N_ * PSTR);
    float*    xt2   = (float*)alloc((size_t)TENC * N_ * IN_ * 4);
    uint32_t* flags = (uint32_t*)alloc((size_t)(NBLK + 1) * 64);
    uint32_t* genp  = flags + (size_t)NBLK * 16;

    prep_kernel<<<1024, 256, 0, stream>>>(x, xt2, sp0, sp1, flags);

    (void)hipFuncSetAttribute((const void*)lsnn_persist,
                              hipFuncAttributeMaxDynamicSharedMemorySize, SMEM_TOT);
    lsnn_persist<<<NBLK, 512, SMEM_TOT, stream>>>(
        xt2, Wi, b_i2h, Wh, b_h2h, Wo, b_h2o, tau_h, tau_o,
        sp0, sp1, flags, genp, out);
}

// Round 10
// 1520.353 us; speedup vs baseline: 1.5839x; 1.0337x over previous
//
#include <hip/hip_runtime.h>
#include <math.h>
#include <stdint.h>

namespace {
constexpr int N_    = 2048;
constexpr int H_    = 800;
constexpr int IN_   = 28;
constexpr int TENC  = 28;
constexpr int TTOT  = 78;             // 28 encode + 50 decode
constexpr int ONUM  = 10;
constexpr int PODS  = 8;              // independent 256-sample pods
constexpr int PBLK  = 26;             // 25 hidden tiles + 1 output block per pod
constexpr int NBLK  = PODS * PBLK;    // 208
constexpr int PSTR  = 128;            // packed spike row stride (bytes); 104 used
constexpr int PDW   = 26;             // dwords used per packed row
constexpr int NSEG  = 13 * 4 * 2;     // (c, digit k, neuron-half) B segments
constexpr int SMEM_B = NSEG * 1024;          // 106496: fragment-ordered digit planes
constexpr int SMEM_W = IN_ * 32 * 4;         // 3584: Wi tile
constexpr int AROW  = 27;                    // LDS A-strip row stride (dwords)
constexpr int SMEM_A = 8 * 32 * AROW * 4;    // 27648: per-wave A strips
constexpr int SMEM_TOT = SMEM_B + SMEM_W + SMEM_A;  // 137728 <= 160K -> 1 blk/CU
}

typedef __attribute__((ext_vector_type(4))) int v4i;

// balanced base-256 digits of round(w * 2^32); exact for |w| < ~0.49
__device__ __forceinline__ void digitize(float w, int8_t d[4]) {
    double dd = (double)w * 4294967296.0;
    long long r = (long long)rint(dd);
    int8_t d0 = (int8_t)(r & 255); r = (r - (long long)d0) >> 8;
    int8_t d1 = (int8_t)(r & 255); r = (r - (long long)d1) >> 8;
    int8_t d2 = (int8_t)(r & 255); r = (r - (long long)d2) >> 8;
    long long r3 = r; r3 = r3 > 127 ? 127 : (r3 < -128 ? -128 : r3);
    d[0] = d0; d[1] = d1; d[2] = d2; d[3] = (int8_t)r3;
}

// expand 16 spike bits -> 16 bytes (0/1) as v4i
__device__ __forceinline__ v4i unpack16(uint32_t u) {
    v4i f;
    f[0] = (int)((((u      ) & 0xFu) * 0x00204081u) & 0x01010101u);
    f[1] = (int)((((u >>  4) & 0xFu) * 0x00204081u) & 0x01010101u);
    f[2] = (int)((((u >>  8) & 0xFu) * 0x00204081u) & 0x01010101u);
    f[3] = (int)((((u >> 12) & 0xFu) * 0x00204081u) & 0x01010101u);
    return f;
}

// ---- pod-local grid barrier: 26 blocks, per-block flag lines, direct scan --
__device__ __forceinline__ void pod_barrier(uint32_t* __restrict__ flags,
                                            int pod, int l, uint32_t epoch) {
    __syncthreads();   // all waves drain vmcnt (sc1 spike stores visible at LLC)
    if (threadIdx.x < 64) {
        if (threadIdx.x == 0) {
            asm volatile("s_waitcnt vmcnt(0)" ::: "memory");
            __hip_atomic_store(flags + ((size_t)pod * PBLK + l) * 16, epoch,
                               __ATOMIC_RELAXED, __HIP_MEMORY_SCOPE_AGENT);
        }
        const bool mine = (threadIdx.x < PBLK);
        bool done = false;
        while (!done) {
            bool ok = true;
            if (mine)
                ok = (__hip_atomic_load(flags + ((size_t)pod * PBLK + threadIdx.x) * 16,
                        __ATOMIC_RELAXED, __HIP_MEMORY_SCOPE_AGENT) >= epoch);
            done = (__ballot(ok) == ~0ull);
            if (!done) __builtin_amdgcn_s_sleep(1);
        }
    }
    __syncthreads();
}

// ---------------------------------------------------------------------------
// prepass: transpose x into xt2[t][n][c], zero packed spike buffers + flags
// ---------------------------------------------------------------------------
__global__ void prep_kernel(const float* __restrict__ x, float* __restrict__ xt2,
                            uint32_t* __restrict__ sp0, uint32_t* __restrict__ sp1,
                            uint32_t* __restrict__ flags)
{
    size_t idx = (size_t)blockIdx.x * blockDim.x + threadIdx.x;
    size_t stride = (size_t)gridDim.x * blockDim.x;
    const size_t TOT = (size_t)TENC * N_ * IN_;
    for (size_t e = idx; e < TOT; e += stride) {
        int t = (int)(e / (N_ * IN_));
        int rem = (int)(e % (N_ * IN_));
        int n = rem / IN_, c = rem % IN_;
        xt2[e] = x[(size_t)n * 784 + c * TENC + t];
    }
    const size_t PW = (size_t)N_ * PSTR / 4;
    for (size_t e = idx; e < PW; e += stride) { sp0[e] = 0u; sp1[e] = 0u; }
    for (size_t e = idx; e < (size_t)NBLK * 16; e += stride) flags[e] = 0u;
}

// ---------------------------------------------------------------------------
// Persistent LSNN, pod-local sync: 8 pods x (25 hidden blocks + 1 o-block).
// B digit planes in LDS, spikes bit-packed + sc1-coherent in global,
// ALL neuron state in registers. No global barrier, no register cap.
// ---------------------------------------------------------------------------
__global__ __launch_bounds__(512)
void lsnn_persist(const float* __restrict__ xt2,
                  const float* __restrict__ Wi,
                  const float* __restrict__ b_i2h,
                  const float* __restrict__ Wh,
                  const float* __restrict__ b_h2h,
                  const float* __restrict__ Wo,
                  const float* __restrict__ b_h2o,
                  const float* __restrict__ tau_h,
                  const float* __restrict__ tau_o,
                  uint32_t* sp0, uint32_t* sp1,
                  uint32_t* flags,
                  float* __restrict__ out)
{
    extern __shared__ __align__(16) int8_t smem[];
    int8_t*   Bl  = smem;                                   // [NSEG][64][16]
    float*    wl  = (float*)(smem + SMEM_B);                // [28][32]
    uint32_t* Alds = (uint32_t*)(smem + SMEM_B + SMEM_W);   // [8 waves][32][AROW]

    const int bid  = blockIdx.x;
    const int pod  = bid / PBLK;          // 0..7 (sample group)
    const int l    = bid % PBLK;          // 0..25 (25 = o-block)
    const bool is_o = (l == 25);
    const int it   = is_o ? 0 : l;
    const int ng   = pod;
    const int i0   = it * 32;
    const int wv   = threadIdx.x >> 6;
    const int lane = threadIdx.x & 63;
    const int quad = lane >> 4;
    const int col  = lane & 15;
    const int n0   = ng * 256 + wv * 32;
    uint32_t* ldsA = Alds + wv * 32 * AROW;
    const int dsel = (quad >> 1);
    const int dsh  = (quad & 1) * 16;

    // ---- build B digit fragments in LDS (once) ----
    for (int e = threadIdx.x; e < 13 * 2 * 64; e += 512) {
        int c  = e >> 7;
        int bh = (e >> 6) & 1;
        int ln = e & 63;
        int q  = ln >> 4, cl = ln & 15;
        int kbase = c * 64 + q * 16;
        uint32_t w4[4][4] = {};
        int row = bh * 16 + cl;
        #pragma unroll
        for (int j = 0; j < 16; ++j) {
            int kidx = kbase + j;
            float w = 0.f;
            if (kidx < H_) {
                if (!is_o) w = Wh[(size_t)(i0 + row) * H_ + kidx];
                else if (bh == 0 && cl < ONUM) w = Wo[(size_t)cl * H_ + kidx];
            }
            int8_t d[4]; digitize(w, d);
            #pragma unroll
            for (int k = 0; k < 4; ++k)
                w4[k][j >> 2] |= ((uint32_t)(uint8_t)d[k]) << ((j & 3) * 8);
        }
        #pragma unroll
        for (int k = 0; k < 4; ++k) {
            v4i v; v[0] = (int)w4[k][0]; v[1] = (int)w4[k][1];
            v[2] = (int)w4[k][2]; v[3] = (int)w4[k][3];
            *(v4i*)(Bl + (((c * 8) + k * 2 + bh) << 10) + (ln << 4)) = v;
        }
    }
    if (!is_o) {
        for (int e = threadIdx.x; e < IN_ * 32; e += 512) {
            int c = e >> 5, il = e & 31;
            wl[c * 32 + il] = Wi[(size_t)(i0 + il) * IN_ + c];
        }
    }

    // ---- constants & register state ----
    const float alpha = (float)exp((double)(-1.0f / 20.0f));
    const float onem  = 1.0f - alpha;
    const double INV32 = 1.0 / 4294967296.0;

    float roB[2] = {}, biB[2] = {}, bhB[2] = {};
    float hm[2][2][4] = {}, hbv[2][2][4];
    float om[2][4] = {}, ospv[2][4] = {}, obb[2][4], cnt[2][4] = {};
    float roO = 0.f, boO = 0.f;
    uint32_t pmask = 0;   // prev spikes for this lane's 16 outputs

    if (!is_o) {
        #pragma unroll
        for (int b = 0; b < 2; ++b) {
            int i = i0 + b * 16 + col;
            float arg = -1.0f / tau_h[i];
            roB[b] = (float)exp((double)arg);
            biB[b] = b_i2h[i]; bhB[b] = b_h2h[i];
        }
        #pragma unroll
        for (int a = 0; a < 2; ++a)
            #pragma unroll
            for (int b = 0; b < 2; ++b)
                #pragma unroll
                for (int r = 0; r < 4; ++r) hbv[a][b][r] = 0.01f;
    } else {
        if (col < ONUM) {
            float arg = -1.0f / tau_o[col];
            roO = (float)exp((double)arg);
            boO = b_h2o[col];
        }
        #pragma unroll
        for (int a = 0; a < 2; ++a)
            #pragma unroll
            for (int r = 0; r < 4; ++r) obb[a][r] = 0.01f;
    }

    __syncthreads();
    uint32_t epoch = 1;

    // ---- time loop ----
    for (int t = 0; t <= TTOT; ++t) {
        const uint32_t* rdP = (t & 1) ? sp1 : sp0;
        uint32_t*       wrP = (t & 1) ? sp0 : sp1;

        const bool active = is_o ? (t >= 1) : (t < TTOT);

        if (active) {
            // stage this wave's 32 packed A rows into LDS (coalesced sc1)
            #pragma unroll
            for (int k = 0; k < 13; ++k) {
                int e = k * 64 + lane;
                int row = e / PDW, d = e - row * PDW;
                uint32_t v = __hip_atomic_load(rdP + (size_t)(n0 + row) * (PSTR / 4) + d,
                                               __ATOMIC_RELAXED, __HIP_MEMORY_SCOPE_AGENT);
                ldsA[row * AROW + d] = v;
            }
        }

        if (!is_o && active) {
            // input projection (encode steps): fp64 exact, fp32-rounded once
            float inpf[2][2][4] = {};
            if (t < TENC) {
                #pragma unroll
                for (int a = 0; a < 2; ++a) {
                    #pragma unroll
                    for (int r = 0; r < 4; ++r) {
                        int n = n0 + a * 16 + quad * 4 + r;
                        const float* xp = xt2 + ((size_t)t * N_ + n) * IN_;
                        double s0 = 0.0, s1 = 0.0;
                        #pragma unroll
                        for (int c = 0; c < IN_; ++c) {
                            double xv = (double)xp[c];
                            s0 += xv * (double)wl[c * 32 + col];
                            s1 += xv * (double)wl[c * 32 + 16 + col];
                        }
                        inpf[a][0][r] = (float)s0;
                        inpf[a][1][r] = (float)s1;
                    }
                }
            }

            v4i acc4[2][2][4] = {};
            #pragma unroll
            for (int c = 0; c < 13; ++c) {
                uint32_t d0 = ldsA[col * AROW + c * 2 + dsel];
                uint32_t d1 = ldsA[(16 + col) * AROW + c * 2 + dsel];
                v4i a0 = unpack16((d0 >> dsh) & 0xFFFFu);
                v4i a1 = unpack16((d1 >> dsh) & 0xFFFFu);
                #pragma unroll
                for (int k = 0; k < 4; ++k) {
                    v4i b0 = *(const v4i*)(Bl + (((c * 8) + k * 2 + 0) << 10) + (lane << 4));
                    v4i b1 = *(const v4i*)(Bl + (((c * 8) + k * 2 + 1) << 10) + (lane << 4));
                    acc4[0][0][k] = __builtin_amdgcn_mfma_i32_16x16x64_i8(a0, b0, acc4[0][0][k], 0, 0, 0);
                    acc4[0][1][k] = __builtin_amdgcn_mfma_i32_16x16x64_i8(a0, b1, acc4[0][1][k], 0, 0, 0);
                    acc4[1][0][k] = __builtin_amdgcn_mfma_i32_16x16x64_i8(a1, b0, acc4[1][0][k], 0, 0, 0);
                    acc4[1][1][k] = __builtin_amdgcn_mfma_i32_16x16x64_i8(a1, b1, acc4[1][1][k], 0, 0, 0);
                }
            }

            // hidden epilogue: fp32, reference order, no FMA; state in registers
            uint32_t nmask = 0;
            {
                #pragma clang fp contract(off)
                #pragma unroll
                for (int a = 0; a < 2; ++a) {
                    #pragma unroll
                    for (int b = 0; b < 2; ++b) {
                        #pragma unroll
                        for (int r = 0; r < 4; ++r) {
                            int sidx = ((a * 2 + b) * 4 + r);
                            int64_t tot = ((int64_t)acc4[a][b][3][r] << 24)
                                        + ((int64_t)acc4[a][b][2][r] << 16)
                                        + ((int64_t)acc4[a][b][1][r] << 8)
                                        +  (int64_t)acc4[a][b][0][r];
                            float rec = (float)((double)tot * INV32);
                            float h_in = ((inpf[a][b][r] + biB[b]) + rec) + bhB[b];
                            float sp = (pmask >> sidx) & 1u ? 1.0f : 0.0f;
                            float ro = roB[b];
                            float bnew = (ro * hbv[a][b][r]) + ((1.0f - ro) * sp);
                            float B = 0.01f + (1.8f * bnew);
                            float mem = ((hm[a][b][r] * alpha) + (onem * h_in)) - (B * sp);
                            float s = (mem - B) > 0.f ? 1.f : 0.f;
                            hbv[a][b][r] = bnew; hm[a][b][r] = mem;
                            if (s > 0.5f) nmask |= (1u << sidx);
                        }
                    }
                }
            }
            pmask = nmask;

            // pack spikes: ballots -> one 32-bit word per row (this block's i-tile)
            #pragma unroll
            for (int a = 0; a < 2; ++a) {
                #pragma unroll
                for (int r = 0; r < 4; ++r) {
                    unsigned long long bal0 = __ballot((nmask >> (a * 8 + r)) & 1u);
                    unsigned long long bal1 = __ballot((nmask >> (a * 8 + 4 + r)) & 1u);
                    if (col == a * 4 + r) {
                        uint32_t w = (uint32_t)((bal0 >> (quad * 16)) & 0xFFFFull)
                                   | ((uint32_t)((bal1 >> (quad * 16)) & 0xFFFFull) << 16);
                        int n = n0 + a * 16 + quad * 4 + r;
                        __hip_atomic_store(wrP + (size_t)n * (PSTR / 4) + it, w,
                                           __ATOMIC_RELAXED, __HIP_MEMORY_SCOPE_AGENT);
                    }
                }
            }
        }

        if (is_o && active) {
            v4i oacc[2][4] = {};
            #pragma unroll
            for (int c = 0; c < 13; ++c) {
                uint32_t d0 = ldsA[col * AROW + c * 2 + dsel];
                uint32_t d1 = ldsA[(16 + col) * AROW + c * 2 + dsel];
                v4i a0 = unpack16((d0 >> dsh) & 0xFFFFu);
                v4i a1 = unpack16((d1 >> dsh) & 0xFFFFu);
                #pragma unroll
                for (int k = 0; k < 4; ++k) {
                    v4i bo = *(const v4i*)(Bl + (((c * 8) + k * 2 + 0) << 10) + (lane << 4));
                    oacc[0][k] = __builtin_amdgcn_mfma_i32_16x16x64_i8(a0, bo, oacc[0][k], 0, 0, 0);
                    oacc[1][k] = __builtin_amdgcn_mfma_i32_16x16x64_i8(a1, bo, oacc[1][k], 0, 0, 0);
                }
            }
            if (col < ONUM) {
                #pragma clang fp contract(off)
                const bool msk = (t - 1) >= TENC;
                #pragma unroll
                for (int a = 0; a < 2; ++a) {
                    #pragma unroll
                    for (int r = 0; r < 4; ++r) {
                        int64_t tot = ((int64_t)oacc[a][3][r] << 24)
                                    + ((int64_t)oacc[a][2][r] << 16)
                                    + ((int64_t)oacc[a][1][r] << 8)
                                    +  (int64_t)oacc[a][0][r];
                        float o_in = ((float)((double)tot * INV32)) + boO;
                        float osp_ = ospv[a][r];
                        float bnew = (roO * obb[a][r]) + ((1.0f - roO) * osp_);
                        float B = 0.01f + (1.8f * bnew);
                        float mem = ((om[a][r] * alpha) + (onem * o_in)) - (B * osp_);
                        float s = (mem - B) > 0.f ? 1.f : 0.f;
                        obb[a][r] = bnew; om[a][r] = mem; ospv[a][r] = s;
                        if (msk) cnt[a][r] += s;
                    }
                }
            }
        }

        if (t < TTOT) pod_barrier(flags, pod, l, epoch++);
    }

    // ---- write spike counts ----
    if (is_o && col < ONUM) {
        #pragma unroll
        for (int a = 0; a < 2; ++a)
            #pragma unroll
            for (int r = 0; r < 4; ++r) {
                int n = n0 + a * 16 + quad * 4 + r;
                out[(size_t)n * ONUM + col] = cnt[a][r];
            }
    }
}

// ---------------------------------------------------------------------------
extern "C" void kernel_launch(void* const* d_in, const int* in_sizes, int n_in,
                              void* d_out, int out_size, void* d_ws, size_t ws_size,
                              hipStream_t stream)
{
    const float* x      = (const float*)d_in[0];
    const float* Wi     = (const float*)d_in[1];
    const float* b_i2h  = (const float*)d_in[2];
    const float* Wh     = (const float*)d_in[3];
    const float* b_h2h  = (const float*)d_in[4];
    const float* Wo     = (const float*)d_in[5];
    const float* b_h2o  = (const float*)d_in[6];
    const float* tau_h  = (const float*)d_in[7];
    const float* tau_o  = (const float*)d_in[8];
    float* out = (float*)d_out;

    uintptr_t p = (uintptr_t)d_ws;
    auto alloc = [&](size_t bytes) -> void* {
        p = (p + 255) & ~(uintptr_t)255;
        void* r = (void*)p; p += bytes; return r;
    };
    uint32_t* sp0   = (uint32_t*)alloc((size_t)N_ * PSTR);
    uint32_t* sp1   = (uint32_t*)alloc((size_t)N_ * PSTR);
    float*    xt2   = (float*)alloc((size_t)TENC * N_ * IN_ * 4);
    uint32_t* flags = (uint32_t*)alloc((size_t)NBLK * 64);

    prep_kernel<<<1024, 256, 0, stream>>>(x, xt2, sp0, sp1, flags);

    (void)hipFuncSetAttribute((const void*)lsnn_persist,
                              hipFuncAttributeMaxDynamicSharedMemorySize, SMEM_TOT);
    lsnn_persist<<<NBLK, 512, SMEM_TOT, stream>>>(
        xt2, Wi, b_i2h, Wh, b_h2h, Wo, b_h2o, tau_h, tau_o,
        sp0, sp1, flags, out);
}

// Round 11
// 1515.892 us; speedup vs baseline: 1.5885x; 1.0029x over previous
//
#include <hip/hip_runtime.h>
#include <math.h>
#include <stdint.h>

namespace {
constexpr int N_    = 2048;
constexpr int H_    = 800;
constexpr int IN_   = 28;
constexpr int TENC  = 28;
constexpr int TTOT  = 78;             // 28 encode + 50 decode
constexpr int ONUM  = 10;
constexpr int PODS  = 8;              // independent 256-sample pods
constexpr int PBLK  = 26;             // 25 hidden tiles + 1 output block per pod
constexpr int NBLK  = PODS * PBLK;    // 208
constexpr int PSTR  = 128;            // packed spike row stride (bytes); 104 used
constexpr int PDW   = 26;             // dwords used per packed row
constexpr int NSEG  = 13 * 4 * 2;     // (c, digit k, neuron-half) B segments
constexpr int SMEM_B = NSEG * 1024;          // 106496: fragment-ordered digit planes
constexpr int SMEM_W = IN_ * 32 * 4;         // 3584: Wi tile
constexpr int AROW  = 27;                    // LDS A-strip row stride (dwords)
constexpr int SMEM_A = 8 * 32 * AROW * 4;    // 27648: per-wave A strips
constexpr int SMEM_TOT = SMEM_B + SMEM_W + SMEM_A;  // 137728 <= 160K -> 1 blk/CU
}

typedef __attribute__((ext_vector_type(4))) int v4i;

// balanced base-256 digits of round(w * 2^32); exact for |w| < ~0.49
__device__ __forceinline__ void digitize(float w, int8_t d[4]) {
    double dd = (double)w * 4294967296.0;
    long long r = (long long)rint(dd);
    int8_t d0 = (int8_t)(r & 255); r = (r - (long long)d0) >> 8;
    int8_t d1 = (int8_t)(r & 255); r = (r - (long long)d1) >> 8;
    int8_t d2 = (int8_t)(r & 255); r = (r - (long long)d2) >> 8;
    long long r3 = r; r3 = r3 > 127 ? 127 : (r3 < -128 ? -128 : r3);
    d[0] = d0; d[1] = d1; d[2] = d2; d[3] = (int8_t)r3;
}

// expand 16 spike bits -> 16 bytes (0/1) as v4i
__device__ __forceinline__ v4i unpack16(uint32_t u) {
    v4i f;
    f[0] = (int)((((u      ) & 0xFu) * 0x00204081u) & 0x01010101u);
    f[1] = (int)((((u >>  4) & 0xFu) * 0x00204081u) & 0x01010101u);
    f[2] = (int)((((u >>  8) & 0xFu) * 0x00204081u) & 0x01010101u);
    f[3] = (int)((((u >> 12) & 0xFu) * 0x00204081u) & 0x01010101u);
    return f;
}

// ---- pod-local grid barrier: 26 blocks, per-block flag lines, direct scan --
__device__ __forceinline__ void pod_barrier(uint32_t* __restrict__ flags,
                                            int pod, int l, uint32_t epoch) {
    __syncthreads();   // all waves drain vmcnt (sc1 spike stores visible at LLC)
    if (threadIdx.x < 64) {
        if (threadIdx.x == 0) {
            asm volatile("s_waitcnt vmcnt(0)" ::: "memory");
            __hip_atomic_store(flags + ((size_t)pod * PBLK + l) * 16, epoch,
                               __ATOMIC_RELAXED, __HIP_MEMORY_SCOPE_AGENT);
        }
        const bool mine = (threadIdx.x < PBLK);
        bool done = false;
        while (!done) {
            bool ok = true;
            if (mine)
                ok = (__hip_atomic_load(flags + ((size_t)pod * PBLK + threadIdx.x) * 16,
                        __ATOMIC_RELAXED, __HIP_MEMORY_SCOPE_AGENT) >= epoch);
            done = (__ballot(ok) == ~0ull);
            if (!done) __builtin_amdgcn_s_sleep(1);
        }
    }
    __syncthreads();
}

// ---------------------------------------------------------------------------
// prepass: transpose x into xt2[t][n][c], zero packed spike buffers + flags
// ---------------------------------------------------------------------------
__global__ void prep_kernel(const float* __restrict__ x, float* __restrict__ xt2,
                            uint32_t* __restrict__ sp0, uint32_t* __restrict__ sp1,
                            uint32_t* __restrict__ flags)
{
    size_t idx = (size_t)blockIdx.x * blockDim.x + threadIdx.x;
    size_t stride = (size_t)gridDim.x * blockDim.x;
    const size_t TOT = (size_t)TENC * N_ * IN_;
    for (size_t e = idx; e < TOT; e += stride) {
        int t = (int)(e / (N_ * IN_));
        int rem = (int)(e % (N_ * IN_));
        int n = rem / IN_, c = rem % IN_;
        xt2[e] = x[(size_t)n * 784 + c * TENC + t];
    }
    const size_t PW = (size_t)N_ * PSTR / 4;
    for (size_t e = idx; e < PW; e += stride) { sp0[e] = 0u; sp1[e] = 0u; }
    for (size_t e = idx; e < (size_t)NBLK * 16; e += stride) flags[e] = 0u;
}

// ---------------------------------------------------------------------------
// Persistent LSNN, pod-local sync: 8 pods x (25 hidden blocks + 1 o-block).
// B digit planes in LDS, spikes bit-packed + sc1-coherent in global,
// ALL neuron state in registers. waves_per_eu(2): 256-VGPR budget, no spills
// (LDS 137728 B already enforces 1 block/CU = 2 waves/SIMD).
// ---------------------------------------------------------------------------
__global__ __launch_bounds__(512)
__attribute__((amdgpu_waves_per_eu(2)))
void lsnn_persist(const float* __restrict__ xt2,
                  const float* __restrict__ Wi,
                  const float* __restrict__ b_i2h,
                  const float* __restrict__ Wh,
                  const float* __restrict__ b_h2h,
                  const float* __restrict__ Wo,
                  const float* __restrict__ b_h2o,
                  const float* __restrict__ tau_h,
                  const float* __restrict__ tau_o,
                  uint32_t* sp0, uint32_t* sp1,
                  uint32_t* flags,
                  float* __restrict__ out)
{
    extern __shared__ __align__(16) int8_t smem[];
    int8_t*   Bl  = smem;                                   // [NSEG][64][16]
    float*    wl  = (float*)(smem + SMEM_B);                // [28][32]
    uint32_t* Alds = (uint32_t*)(smem + SMEM_B + SMEM_W);   // [8 waves][32][AROW]

    const int bid  = blockIdx.x;
    const int pod  = bid / PBLK;          // 0..7 (sample group)
    const int l    = bid % PBLK;          // 0..25 (25 = o-block)
    const bool is_o = (l == 25);
    const int it   = is_o ? 0 : l;
    const int ng   = pod;
    const int i0   = it * 32;
    const int wv   = threadIdx.x >> 6;
    const int lane = threadIdx.x & 63;
    const int quad = lane >> 4;
    const int col  = lane & 15;
    const int n0   = ng * 256 + wv * 32;
    uint32_t* ldsA = Alds + wv * 32 * AROW;
    const int dsel = (quad >> 1);
    const int dsh  = (quad & 1) * 16;

    // ---- build B digit fragments in LDS (once) ----
    for (int e = threadIdx.x; e < 13 * 2 * 64; e += 512) {
        int c  = e >> 7;
        int bh = (e >> 6) & 1;
        int ln = e & 63;
        int q  = ln >> 4, cl = ln & 15;
        int kbase = c * 64 + q * 16;
        uint32_t w4[4][4] = {};
        int row = bh * 16 + cl;
        #pragma unroll
        for (int j = 0; j < 16; ++j) {
            int kidx = kbase + j;
            float w = 0.f;
            if (kidx < H_) {
                if (!is_o) w = Wh[(size_t)(i0 + row) * H_ + kidx];
                else if (bh == 0 && cl < ONUM) w = Wo[(size_t)cl * H_ + kidx];
            }
            int8_t d[4]; digitize(w, d);
            #pragma unroll
            for (int k = 0; k < 4; ++k)
                w4[k][j >> 2] |= ((uint32_t)(uint8_t)d[k]) << ((j & 3) * 8);
        }
        #pragma unroll
        for (int k = 0; k < 4; ++k) {
            v4i v; v[0] = (int)w4[k][0]; v[1] = (int)w4[k][1];
            v[2] = (int)w4[k][2]; v[3] = (int)w4[k][3];
            *(v4i*)(Bl + (((c * 8) + k * 2 + bh) << 10) + (ln << 4)) = v;
        }
    }
    if (!is_o) {
        for (int e = threadIdx.x; e < IN_ * 32; e += 512) {
            int c = e >> 5, il = e & 31;
            wl[c * 32 + il] = Wi[(size_t)(i0 + il) * IN_ + c];
        }
    }

    // ---- constants & register state ----
    const float alpha = (float)exp((double)(-1.0f / 20.0f));
    const float onem  = 1.0f - alpha;
    const double INV32 = 1.0 / 4294967296.0;

    float roB[2] = {}, biB[2] = {}, bhB[2] = {};
    float hm[2][2][4] = {}, hbv[2][2][4];
    float om[2][4] = {}, ospv[2][4] = {}, obb[2][4], cnt[2][4] = {};
    float roO = 0.f, boO = 0.f;
    uint32_t pmask = 0;   // prev spikes for this lane's 16 outputs

    if (!is_o) {
        #pragma unroll
        for (int b = 0; b < 2; ++b) {
            int i = i0 + b * 16 + col;
            float arg = -1.0f / tau_h[i];
            roB[b] = (float)exp((double)arg);
            biB[b] = b_i2h[i]; bhB[b] = b_h2h[i];
        }
        #pragma unroll
        for (int a = 0; a < 2; ++a)
            #pragma unroll
            for (int b = 0; b < 2; ++b)
                #pragma unroll
                for (int r = 0; r < 4; ++r) hbv[a][b][r] = 0.01f;
    } else {
        if (col < ONUM) {
            float arg = -1.0f / tau_o[col];
            roO = (float)exp((double)arg);
            boO = b_h2o[col];
        }
        #pragma unroll
        for (int a = 0; a < 2; ++a)
            #pragma unroll
            for (int r = 0; r < 4; ++r) obb[a][r] = 0.01f;
    }

    __syncthreads();
    uint32_t epoch = 1;

    // ---- time loop ----
    for (int t = 0; t <= TTOT; ++t) {
        const uint32_t* rdP = (t & 1) ? sp1 : sp0;
        uint32_t*       wrP = (t & 1) ? sp0 : sp1;

        const bool active = is_o ? (t >= 1) : (t < TTOT);

        if (active) {
            // stage this wave's 32 packed A rows into LDS (coalesced sc1)
            #pragma unroll
            for (int k = 0; k < 13; ++k) {
                int e = k * 64 + lane;
                int row = e / PDW, d = e - row * PDW;
                uint32_t v = __hip_atomic_load(rdP + (size_t)(n0 + row) * (PSTR / 4) + d,
                                               __ATOMIC_RELAXED, __HIP_MEMORY_SCOPE_AGENT);
                ldsA[row * AROW + d] = v;
            }
        }

        if (!is_o && active) {
            // input projection (encode steps): fp64 exact, fp32-rounded once
            float inpf[2][2][4] = {};
            if (t < TENC) {
                #pragma unroll
                for (int a = 0; a < 2; ++a) {
                    #pragma unroll
                    for (int r = 0; r < 4; ++r) {
                        int n = n0 + a * 16 + quad * 4 + r;
                        const float* xp = xt2 + ((size_t)t * N_ + n) * IN_;
                        double s0 = 0.0, s1 = 0.0;
                        #pragma unroll
                        for (int c = 0; c < IN_; ++c) {
                            double xv = (double)xp[c];
                            s0 += xv * (double)wl[c * 32 + col];
                            s1 += xv * (double)wl[c * 32 + 16 + col];
                        }
                        inpf[a][0][r] = (float)s0;
                        inpf[a][1][r] = (float)s1;
                    }
                }
            }

            v4i acc4[2][2][4] = {};
            #pragma unroll
            for (int c = 0; c < 13; ++c) {
                uint32_t d0 = ldsA[col * AROW + c * 2 + dsel];
                uint32_t d1 = ldsA[(16 + col) * AROW + c * 2 + dsel];
                v4i a0 = unpack16((d0 >> dsh) & 0xFFFFu);
                v4i a1 = unpack16((d1 >> dsh) & 0xFFFFu);
                #pragma unroll
                for (int k = 0; k < 4; ++k) {
                    v4i b0 = *(const v4i*)(Bl + (((c * 8) + k * 2 + 0) << 10) + (lane << 4));
                    v4i b1 = *(const v4i*)(Bl + (((c * 8) + k * 2 + 1) << 10) + (lane << 4));
                    acc4[0][0][k] = __builtin_amdgcn_mfma_i32_16x16x64_i8(a0, b0, acc4[0][0][k], 0, 0, 0);
                    acc4[0][1][k] = __builtin_amdgcn_mfma_i32_16x16x64_i8(a0, b1, acc4[0][1][k], 0, 0, 0);
                    acc4[1][0][k] = __builtin_amdgcn_mfma_i32_16x16x64_i8(a1, b0, acc4[1][0][k], 0, 0, 0);
                    acc4[1][1][k] = __builtin_amdgcn_mfma_i32_16x16x64_i8(a1, b1, acc4[1][1][k], 0, 0, 0);
                }
            }

            // hidden epilogue: fp32, reference order, no FMA; state in registers
            uint32_t nmask = 0;
            {
                #pragma clang fp contract(off)
                #pragma unroll
                for (int a = 0; a < 2; ++a) {
                    #pragma unroll
                    for (int b = 0; b < 2; ++b) {
                        #pragma unroll
                        for (int r = 0; r < 4; ++r) {
                            int sidx = ((a * 2 + b) * 4 + r);
                            int64_t tot = ((int64_t)acc4[a][b][3][r] << 24)
                                        + ((int64_t)acc4[a][b][2][r] << 16)
                                        + ((int64_t)acc4[a][b][1][r] << 8)
                                        +  (int64_t)acc4[a][b][0][r];
                            float rec = (float)((double)tot * INV32);
                            float h_in = ((inpf[a][b][r] + biB[b]) + rec) + bhB[b];
                            float sp = (pmask >> sidx) & 1u ? 1.0f : 0.0f;
                            float ro = roB[b];
                            float bnew = (ro * hbv[a][b][r]) + ((1.0f - ro) * sp);
                            float B = 0.01f + (1.8f * bnew);
                            float mem = ((hm[a][b][r] * alpha) + (onem * h_in)) - (B * sp);
                            float s = (mem - B) > 0.f ? 1.f : 0.f;
                            hbv[a][b][r] = bnew; hm[a][b][r] = mem;
                            if (s > 0.5f) nmask |= (1u << sidx);
                        }
                    }
                }
            }
            pmask = nmask;

            // pack spikes: ballots -> one 32-bit word per row (this block's i-tile)
            #pragma unroll
            for (int a = 0; a < 2; ++a) {
                #pragma unroll
                for (int r = 0; r < 4; ++r) {
                    unsigned long long bal0 = __ballot((nmask >> (a * 8 + r)) & 1u);
                    unsigned long long bal1 = __ballot((nmask >> (a * 8 + 4 + r)) & 1u);
                    if (col == a * 4 + r) {
                        uint32_t w = (uint32_t)((bal0 >> (quad * 16)) & 0xFFFFull)
                                   | ((uint32_t)((bal1 >> (quad * 16)) & 0xFFFFull) << 16);
                        int n = n0 + a * 16 + quad * 4 + r;
                        __hip_atomic_store(wrP + (size_t)n * (PSTR / 4) + it, w,
                                           __ATOMIC_RELAXED, __HIP_MEMORY_SCOPE_AGENT);
                    }
                }
            }
        }

        if (is_o && active) {
            v4i oacc[2][4] = {};
            #pragma unroll
            for (int c = 0; c < 13; ++c) {
                uint32_t d0 = ldsA[col * AROW + c * 2 + dsel];
                uint32_t d1 = ldsA[(16 + col) * AROW + c * 2 + dsel];
                v4i a0 = unpack16((d0 >> dsh) & 0xFFFFu);
                v4i a1 = unpack16((d1 >> dsh) & 0xFFFFu);
                #pragma unroll
                for (int k = 0; k < 4; ++k) {
                    v4i bo = *(const v4i*)(Bl + (((c * 8) + k * 2 + 0) << 10) + (lane << 4));
                    oacc[0][k] = __builtin_amdgcn_mfma_i32_16x16x64_i8(a0, bo, oacc[0][k], 0, 0, 0);
                    oacc[1][k] = __builtin_amdgcn_mfma_i32_16x16x64_i8(a1, bo, oacc[1][k], 0, 0, 0);
                }
            }
            if (col < ONUM) {
                #pragma clang fp contract(off)
                const bool msk = (t - 1) >= TENC;
                #pragma unroll
                for (int a = 0; a < 2; ++a) {
                    #pragma unroll
                    for (int r = 0; r < 4; ++r) {
                        int64_t tot = ((int64_t)oacc[a][3][r] << 24)
                                    + ((int64_t)oacc[a][2][r] << 16)
                                    + ((int64_t)oacc[a][1][r] << 8)
                                    +  (int64_t)oacc[a][0][r];
                        float o_in = ((float)((double)tot * INV32)) + boO;
                        float osp_ = ospv[a][r];
                        float bnew = (roO * obb[a][r]) + ((1.0f - roO) * osp_);
                        float B = 0.01f + (1.8f * bnew);
                        float mem = ((om[a][r] * alpha) + (onem * o_in)) - (B * osp_);
                        float s = (mem - B) > 0.f ? 1.f : 0.f;
                        obb[a][r] = bnew; om[a][r] = mem; ospv[a][r] = s;
                        if (msk) cnt[a][r] += s;
                    }
                }
            }
        }

        if (t < TTOT) pod_barrier(flags, pod, l, epoch++);
    }

    // ---- write spike counts ----
    if (is_o && col < ONUM) {
        #pragma unroll
        for (int a = 0; a < 2; ++a)
            #pragma unroll
            for (int r = 0; r < 4; ++r) {
                int n = n0 + a * 16 + quad * 4 + r;
                out[(size_t)n * ONUM + col] = cnt[a][r];
            }
    }
}

// ---------------------------------------------------------------------------
extern "C" void kernel_launch(void* const* d_in, const int* in_sizes, int n_in,
                              void* d_out, int out_size, void* d_ws, size_t ws_size,
                              hipStream_t stream)
{
    const float* x      = (const float*)d_in[0];
    const float* Wi     = (const float*)d_in[1];
    const float* b_i2h  = (const float*)d_in[2];
    const float* Wh     = (const float*)d_in[3];
    const float* b_h2h  = (const float*)d_in[4];
    const float* Wo     = (const float*)d_in[5];
    const float* b_h2o  = (const float*)d_in[6];
    const float* tau_h  = (const float*)d_in[7];
    const float* tau_o  = (const float*)d_in[8];
    float* out = (float*)d_out;

    uintptr_t p = (uintptr_t)d_ws;
    auto alloc = [&](size_t bytes) -> void* {
        p = (p + 255) & ~(uintptr_t)255;
        void* r = (void*)p; p += bytes; return r;
    };
    uint32_t* sp0   = (uint32_t*)alloc((size_t)N_ * PSTR);
    uint32_t* sp1   = (uint32_t*)alloc((size_t)N_ * PSTR);
    float*    xt2   = (float*)alloc((size_t)TENC * N_ * IN_ * 4);
    uint32_t* flags = (uint32_t*)alloc((size_t)NBLK * 64);

    prep_kernel<<<1024, 256, 0, stream>>>(x, xt2, sp0, sp1, flags);

    (void)hipFuncSetAttribute((const void*)lsnn_persist,
                              hipFuncAttributeMaxDynamicSharedMemorySize, SMEM_TOT);
    lsnn_persist<<<NBLK, 512, SMEM_TOT, stream>>>(
        xt2, Wi, b_i2h, Wh, b_h2h, Wo, b_h2o, tau_h, tau_o,
        sp0, sp1, flags, out);
}